// Round 8
// baseline (232.713 us; speedup 1.0000x reference)
//
#include <hip/hip_runtime.h>
#include <hip/hip_bf16.h>
#include <math.h>
#include <stdint.h>

// ScaleAdaptiveRouter on MI355X (gfx950) — Round 19
// T=16384, H=2048, E=64, K=2112, top-2.
//
// R18 (~63us gemm inferred): per-step A-loads still paid exposed latency
// (depth-2 rotation didn't survive codegen; atomics polluted vmcnt).
// R19: the K-loop contains ZERO vmem. Finer K-split (NKR=16) makes a
// block's B-slice 48KB (LDS, staged ONCE) and a wave-iteration's A only
// 8 x 16B loads (32 VGPRs). Per iteration:
//   {issue all 8 A-loads -> sched_barrier(0) -> 4 steps of pure
//    LDS+VALU+MFMA -> 16 atomicAdds}
// -> exposed latency structurally <= 1 load-latency per ~2500cy iter.
// Grid = 16 kr x 32 tgsets = 512 blocks = exactly 2/CU (one generation),
// 256 thr / 4 waves; each block: B once, then 8 iterations x 64 tokens
// (wave = m-tile of 16). Partials atomicAdd into zeroed logits (R18
// proved absmax-neutral); finish kernel (256 blocks now) adds tail +
// noise, top-2, softmax-pair, writes dense output.

#define H_DIM 2048
#define K_TOTAL 2112
#define E_DIM 64
#define SE_DIM 64
#define NSTEP 64                        // total K32 steps over H
#define NKR 16                          // K-split factor
#define KR_LEN 128                      // k floats per kr slice
#define KS_PER_KR 4                     // K32 steps per kr
#define STEP_BYTES (12 * 1024)
#define WP_TOTAL (NSTEP * STEP_BYTES)   // 786432 B
#define BSLICE_BYTES (KS_PER_KR * STEP_BYTES)   // 49152 B = 48 KB
#define LOGITS_OFF (WP_TOTAL + 256)     // ws offset of logits buffer
#define LOGITS_BYTES (16384 * E_DIM * 4)        // 4 MB

typedef float  f32x4 __attribute__((ext_vector_type(4)));
typedef short  s16x8 __attribute__((ext_vector_type(8)));
typedef unsigned int u32x4 __attribute__((ext_vector_type(4)));

typedef uint32_t __attribute__((address_space(1))) gu32_t;
typedef uint32_t __attribute__((address_space(3))) lu32_t;
__device__ __forceinline__ void gload_lds16(const void* g, void* l) {
    __builtin_amdgcn_global_load_lds((const gu32_t*)g, (lu32_t*)l, 16, 0, 0);
}

__device__ __forceinline__ unsigned short bf16_rne(float f) {
    uint32_t u = __float_as_uint(f);
    return (unsigned short)((u + 0x7FFFu + ((u >> 16) & 1u)) >> 16);
}
__device__ __forceinline__ float bf16_f32(unsigned short h) {
    return __uint_as_float(((uint32_t)h) << 16);
}
__device__ __forceinline__ uint32_t bits_of_bf2(__hip_bfloat162 h) {
    uint32_t u; __builtin_memcpy(&u, &h, 4); return u;
}

// ---- prep: split W into 3 bf16 planes laid out as MFMA B-fragments ----
// B-frag (16x16x32): lane l -> n = l&15, k = (l>>4)*8 + j. Record (s,nt,p):
// 64 lanes x 8 bf16 = 1 KB; record index = s*12 + nt*3 + p.  [R6-verified]
// Records are (kr,ks)-nested automatically (s = kr*4 + ks).
__global__ void prep_kernel(const float* __restrict__ W,
                            const float* __restrict__ se,
                            const int* __restrict__ sidx,
                            unsigned short* __restrict__ Wp,
                            float* __restrict__ tail) {
    if (blockIdx.x == 64) {
        int e = threadIdx.x;
        if (e < 64) {
            const float* emb = se + (*sidx) * SE_DIM;
            float t = 0.f;
            for (int j = 0; j < SE_DIM; ++j)
                t = fmaf(emb[j], W[(size_t)e * K_TOTAL + H_DIM + j], t);
            tail[e] = t;
        }
        return;
    }
    int item = blockIdx.x * 256 + threadIdx.x;   // (s, nt, lane)
    int lane = item & 63;
    int nt   = (item >> 6) & 3;
    int s    = item >> 8;
    int e     = nt * 16 + (lane & 15);
    int kbase = s * 32 + (lane >> 4) * 8;
    const float* wr = W + (size_t)e * K_TOTAL + kbase;
    unsigned short p0[8], p1[8], p2[8];
    #pragma unroll
    for (int j = 0; j < 8; ++j) {
        float v = wr[j];
        unsigned short a0 = bf16_rne(v);
        float r1 = v - bf16_f32(a0);
        unsigned short a1 = bf16_rne(r1);
        float r2 = r1 - bf16_f32(a1);
        p0[j] = a0; p1[j] = a1; p2[j] = bf16_rne(r2);
    }
    size_t rec = (size_t)s * 12 + nt * 3;
    unsigned short* d0 = Wp + (rec + 0) * 512 + lane * 8;
    unsigned short* d1 = Wp + (rec + 1) * 512 + lane * 8;
    unsigned short* d2 = Wp + (rec + 2) * 512 + lane * 8;
    #pragma unroll
    for (int j = 0; j < 8; ++j) { d0[j] = p0[j]; d1[j] = p1[j]; d2[j] = p2[j]; }
}

// split 8 consecutive-k floats into 3 bf16 A-fragment planes (packed pairs)
__device__ __forceinline__ void split3(const float4 fa, const float4 fb,
                                       s16x8& P0, s16x8& P1, s16x8& P2) {
    float f[8] = {fa.x, fa.y, fa.z, fa.w, fb.x, fb.y, fb.z, fb.w};
    uint32_t d0[4], d1[4], d2[4];
    #pragma unroll
    for (int p = 0; p < 4; ++p) {
        float v0 = f[2 * p], v1 = f[2 * p + 1];
        uint32_t u0 = bits_of_bf2(__float22bfloat162_rn(make_float2(v0, v1)));
        float r0 = v0 - __uint_as_float(u0 << 16);
        float r1 = v1 - __uint_as_float(u0 & 0xffff0000u);
        uint32_t u1 = bits_of_bf2(__float22bfloat162_rn(make_float2(r0, r1)));
        float s0 = r0 - __uint_as_float(u1 << 16);
        float s1 = r1 - __uint_as_float(u1 & 0xffff0000u);
        uint32_t u2 = bits_of_bf2(__float22bfloat162_rn(make_float2(s0, s1)));
        d0[p] = u0; d1[p] = u1; d2[p] = u2;
    }
    u32x4 q0 = {d0[0], d0[1], d0[2], d0[3]};
    u32x4 q1 = {d1[0], d1[1], d1[2], d1[3]};
    u32x4 q2 = {d2[0], d2[1], d2[2], d2[3]};
    __builtin_memcpy(&P0, &q0, 16);
    __builtin_memcpy(&P1, &q1, 16);
    __builtin_memcpy(&P2, &q2, 16);
}

// ---- stage 1: K-split GEMM, B stationary in LDS, vmem-free K-loop ----
__launch_bounds__(256, 2)
__global__ void gemm_kernel(const float* __restrict__ x,
                            const unsigned char* __restrict__ Wp,
                            float* __restrict__ logits) {
    __shared__ __align__(16) unsigned char Bs[BSLICE_BYTES];   // 48 KB

    const int tid  = threadIdx.x;                    // 0..255
    const int lane = tid & 63;
    const int wave = __builtin_amdgcn_readfirstlane(tid >> 6);  // 0..3 = m-tile
    const int kr   = blockIdx.x >> 5;                // 0..15 K-range
    const int tgs  = blockIdx.x & 31;                // 0..31 token superset
    const int row  = lane & 15;
    const int quad = lane >> 4;
    const int c    = row;                            // expert col in 16-slice

    // ---- B preload: 48 KB once (12 glds/thread, lane-linear dst) ----
    {
        const unsigned char* bsrc = Wp + (size_t)kr * BSLICE_BYTES + tid * 16;
        #pragma unroll
        for (int i = 0; i < 12; ++i)
            gload_lds16(bsrc + i * 4096, &Bs[tid * 16 + i * 4096]);
        asm volatile("s_waitcnt vmcnt(0)" ::: "memory");
        __syncthreads();
    }

    // wave handles tokens tgs*512 + it*64 + wave*16 + row, it = 0..7
    const float* ap = x + (size_t)(tgs * 512 + wave * 16 + row) * H_DIM
                        + kr * KR_LEN + quad * 8;

    #define COMPUTE(KS, VA, VB) do {                                        \
        s16x8 A0, A1, A2;                                                   \
        split3(VA, VB, A0, A1, A2);                                         \
        const unsigned char* _bb = &Bs[(KS) * STEP_BYTES + lane * 16];      \
        {                                                                   \
            s16x8 B0 = *(const s16x8*)(_bb);                                \
            s16x8 B1 = *(const s16x8*)(_bb + 1024);                         \
            s16x8 B2 = *(const s16x8*)(_bb + 2048);                         \
            acc0 = __builtin_amdgcn_mfma_f32_16x16x32_bf16(A0, B0, acc0, 0, 0, 0); \
            acc0 = __builtin_amdgcn_mfma_f32_16x16x32_bf16(A0, B1, acc0, 0, 0, 0); \
            acc0 = __builtin_amdgcn_mfma_f32_16x16x32_bf16(A1, B0, acc0, 0, 0, 0); \
            acc0 = __builtin_amdgcn_mfma_f32_16x16x32_bf16(A0, B2, acc0, 0, 0, 0); \
            acc0 = __builtin_amdgcn_mfma_f32_16x16x32_bf16(A1, B1, acc0, 0, 0, 0); \
            acc0 = __builtin_amdgcn_mfma_f32_16x16x32_bf16(A2, B0, acc0, 0, 0, 0); \
        }                                                                   \
        {                                                                   \
            s16x8 B0 = *(const s16x8*)(_bb + 3072);                         \
            s16x8 B1 = *(const s16x8*)(_bb + 4096);                         \
            s16x8 B2 = *(const s16x8*)(_bb + 5120);                         \
            acc1 = __builtin_amdgcn_mfma_f32_16x16x32_bf16(A0, B0, acc1, 0, 0, 0); \
            acc1 = __builtin_amdgcn_mfma_f32_16x16x32_bf16(A0, B1, acc1, 0, 0, 0); \
            acc1 = __builtin_amdgcn_mfma_f32_16x16x32_bf16(A1, B0, acc1, 0, 0, 0); \
            acc1 = __builtin_amdgcn_mfma_f32_16x16x32_bf16(A0, B2, acc1, 0, 0, 0); \
            acc1 = __builtin_amdgcn_mfma_f32_16x16x32_bf16(A1, B1, acc1, 0, 0, 0); \
            acc1 = __builtin_amdgcn_mfma_f32_16x16x32_bf16(A2, B0, acc1, 0, 0, 0); \
        }                                                                   \
        {                                                                   \
            s16x8 B0 = *(const s16x8*)(_bb + 6144);                         \
            s16x8 B1 = *(const s16x8*)(_bb + 7168);                         \
            s16x8 B2 = *(const s16x8*)(_bb + 8192);                         \
            acc2 = __builtin_amdgcn_mfma_f32_16x16x32_bf16(A0, B0, acc2, 0, 0, 0); \
            acc2 = __builtin_amdgcn_mfma_f32_16x16x32_bf16(A0, B1, acc2, 0, 0, 0); \
            acc2 = __builtin_amdgcn_mfma_f32_16x16x32_bf16(A1, B0, acc2, 0, 0, 0); \
            acc2 = __builtin_amdgcn_mfma_f32_16x16x32_bf16(A0, B2, acc2, 0, 0, 0); \
            acc2 = __builtin_amdgcn_mfma_f32_16x16x32_bf16(A1, B1, acc2, 0, 0, 0); \
            acc2 = __builtin_amdgcn_mfma_f32_16x16x32_bf16(A2, B0, acc2, 0, 0, 0); \
        }                                                                   \
        {                                                                   \
            s16x8 B0 = *(const s16x8*)(_bb + 9216);                         \
            s16x8 B1 = *(const s16x8*)(_bb + 10240);                        \
            s16x8 B2 = *(const s16x8*)(_bb + 11264);                        \
            acc3 = __builtin_amdgcn_mfma_f32_16x16x32_bf16(A0, B0, acc3, 0, 0, 0); \
            acc3 = __builtin_amdgcn_mfma_f32_16x16x32_bf16(A0, B1, acc3, 0, 0, 0); \
            acc3 = __builtin_amdgcn_mfma_f32_16x16x32_bf16(A1, B0, acc3, 0, 0, 0); \
            acc3 = __builtin_amdgcn_mfma_f32_16x16x32_bf16(A0, B2, acc3, 0, 0, 0); \
            acc3 = __builtin_amdgcn_mfma_f32_16x16x32_bf16(A1, B1, acc3, 0, 0, 0); \
            acc3 = __builtin_amdgcn_mfma_f32_16x16x32_bf16(A2, B0, acc3, 0, 0, 0); \
        }                                                                   \
    } while (0)

    #pragma unroll 1
    for (int it = 0; it < 8; ++it) {
        const float* a = ap + (size_t)it * (64 * H_DIM);
        // ---- issue ALL 8 A-loads for this iteration, then fence ----
        float4 A00 = *(const float4*)(a);
        float4 A01 = *(const float4*)(a + 4);
        float4 A10 = *(const float4*)(a + 32);
        float4 A11 = *(const float4*)(a + 36);
        float4 A20 = *(const float4*)(a + 64);
        float4 A21 = *(const float4*)(a + 68);
        float4 A30 = *(const float4*)(a + 96);
        float4 A31 = *(const float4*)(a + 100);
        __builtin_amdgcn_sched_barrier(0);   // loads stay above compute

        f32x4 acc0 = {0.f, 0.f, 0.f, 0.f}, acc1 = acc0, acc2 = acc0, acc3 = acc0;
        COMPUTE(0, A00, A01);
        COMPUTE(1, A10, A11);
        COMPUTE(2, A20, A21);
        COMPUTE(3, A30, A31);

        // ---- flush partials: 16 atomics, then next iteration ----
        const int tokb = tgs * 512 + it * 64 + wave * 16 + quad * 4;
        float* lg = logits + (size_t)tokb * E_DIM + c;
        #pragma unroll
        for (int r = 0; r < 4; ++r) {
            atomicAdd(lg + r * E_DIM +  0, acc0[r]);
            atomicAdd(lg + r * E_DIM + 16, acc1[r]);
            atomicAdd(lg + r * E_DIM + 32, acc2[r]);
            atomicAdd(lg + r * E_DIM + 48, acc3[r]);
        }
    }
    #undef COMPUTE
}

// ---- stage 2: add tail + noise, top-2, softmax-pair, dense output ----
__launch_bounds__(64, 4)
__global__ void finish_kernel(const float* __restrict__ logits,
                              const float* __restrict__ tail,
                              const float* __restrict__ noise,
                              float* __restrict__ out) {
    const int t = blockIdx.x * 64 + threadIdx.x;     // token 0..16383
    const float4* L4 = (const float4*)(logits + (size_t)t * E_DIM);
    const float4* N4 = (const float4*)(noise  + (size_t)t * E_DIM);
    const float4* T4 = (const float4*)tail;

    float V1 = -3.4e38f, V2 = -3.4e38f;
    int   I1 = 0x7fffffff, I2 = 0x7fffffff;
    #define UPD(V, E) do {                                          \
        float _v = (V); int _e = (E);                               \
        if (_v > V1)      { V2 = V1; I2 = I1; V1 = _v; I1 = _e; }   \
        else if (_v > V2) { V2 = _v; I2 = _e; }                     \
    } while (0)
    #pragma unroll
    for (int i = 0; i < 16; ++i) {
        float4 l = L4[i], n = N4[i], tl = T4[i];
        UPD(l.x + tl.x + 0.1f * n.x, i * 4 + 0);
        UPD(l.y + tl.y + 0.1f * n.y, i * 4 + 1);
        UPD(l.z + tl.z + 0.1f * n.z, i * 4 + 2);
        UPD(l.w + tl.w + 0.1f * n.w, i * 4 + 3);
    }
    #undef UPD
    float d   = expf(V2 - V1);                  // softmax denom cancels
    float inv = 1.0f / (1.0f + d);
    float w1 = inv, w2 = d * inv;

    float4* O4 = (float4*)(out + (size_t)t * E_DIM);
    #pragma unroll
    for (int i = 0; i < 16; ++i) {
        int e = i * 4;
        float4 o;
        o.x = (e + 0 == I1) ? w1 : (e + 0 == I2) ? w2 : 0.0f;
        o.y = (e + 1 == I1) ? w1 : (e + 1 == I2) ? w2 : 0.0f;
        o.z = (e + 2 == I1) ? w1 : (e + 2 == I2) ? w2 : 0.0f;
        o.w = (e + 3 == I1) ? w1 : (e + 3 == I2) ? w2 : 0.0f;
        O4[i] = o;
    }
}

extern "C" void kernel_launch(void* const* d_in, const int* in_sizes, int n_in,
                              void* d_out, int out_size, void* d_ws, size_t ws_size,
                              hipStream_t stream) {
    const float* x     = (const float*)d_in[0];
    const float* se    = (const float*)d_in[1];
    const float* W     = (const float*)d_in[2];
    const float* noise = (const float*)d_in[3];
    const int*   sidx  = (const int*)d_in[4];
    float* out = (float*)d_out;

    unsigned short* Wp     = (unsigned short*)d_ws;                   // 786432 B
    float*          tail   = (float*)((char*)d_ws + WP_TOTAL);        // 256 B
    float*          logits = (float*)((char*)d_ws + LOGITS_OFF);      // 4 MB

    hipMemsetAsync(logits, 0, LOGITS_BYTES, stream);
    hipLaunchKernelGGL(prep_kernel, dim3(65), dim3(256), 0, stream,
                       W, se, sidx, Wp, tail);
    hipLaunchKernelGGL(gemm_kernel, dim3(NKR * 32), dim3(256), 0, stream,
                       x, (const unsigned char*)Wp, logits);
    hipLaunchKernelGGL(finish_kernel, dim3(256), dim3(64), 0, stream,
                       logits, tail, noise, out);
}

// Round 9
// 223.686 us; speedup vs baseline: 1.0404x; 1.0404x over previous
//
#include <hip/hip_runtime.h>
#include <hip/hip_bf16.h>
#include <math.h>
#include <stdint.h>

// ScaleAdaptiveRouter on MI355X (gfx950) — Round 20
// T=16384, H=2048, E=64, K=2112, top-2.
//
// R18/R19: B-stationary-LDS + K-split + atomic partials works (absmax
// 0.0) but controllable time ~75-87us. Cost model: per-CU serial terms =
// LDS b128 reads (~15us), L2 atomics (~13-27us, scales with partial
// count), A-stream (~19us overlappable), MFMA (~3us/SIMD).
// R20 cuts the two big terms, keeping the proven skeleton:
//   (1) atomics /4 vs R19: block covers TWO kr slices sequentially
//       (stage B(2p) -> compute -> restage B(2p+1) -> compute), acc
//       carried in registers, ONE flush -> 4 partials/token-expert.
//   (2) LDS reads /2: wave processes TWO m-tiles per B-record read
//       (B0/B1/B2 in regs feed both acc chains; ds:MFMA = 1:4).
//   (3) zero-vmem compute retained: per burst {8 A-loads ->
//       sched_barrier(0) -> 2 ks x (12 ds_read + 4 split3 + 96 MFMA)}.
// Grid = 4 kr-pairs x 64 token-groups = 256 blocks (96KB LDS -> 1/CU,
// 8 waves), 512 thr; wave owns 32 tokens (2 m-tiles); 2 stages x 4
// bursts. prep/finish unchanged; same fragment bits + 6-term chain
// order -> absmax stays in {0, 0.004}.

#define H_DIM 2048
#define K_TOTAL 2112
#define E_DIM 64
#define SE_DIM 64
#define NSTEP 64                        // total K32 steps over H
#define NKR 8                           // physical K slices (B-slice unit)
#define NPR 4                           // kr-pairs (one block covers 2 kr)
#define STEP_BYTES (12 * 1024)
#define WP_TOTAL (NSTEP * STEP_BYTES)   // 786432 B
#define BSLICE_BYTES (8 * STEP_BYTES)   // 98304 B = 96 KB (8 K-steps)
#define LOGITS_OFF (WP_TOTAL + 256)     // ws offset of logits buffer
#define LOGITS_BYTES (16384 * E_DIM * 4)        // 4 MB

typedef float  f32x4 __attribute__((ext_vector_type(4)));
typedef short  s16x8 __attribute__((ext_vector_type(8)));
typedef unsigned int u32x4 __attribute__((ext_vector_type(4)));

typedef uint32_t __attribute__((address_space(1))) gu32_t;
typedef uint32_t __attribute__((address_space(3))) lu32_t;
__device__ __forceinline__ void gload_lds16(const void* g, void* l) {
    __builtin_amdgcn_global_load_lds((const gu32_t*)g, (lu32_t*)l, 16, 0, 0);
}

__device__ __forceinline__ unsigned short bf16_rne(float f) {
    uint32_t u = __float_as_uint(f);
    return (unsigned short)((u + 0x7FFFu + ((u >> 16) & 1u)) >> 16);
}
__device__ __forceinline__ float bf16_f32(unsigned short h) {
    return __uint_as_float(((uint32_t)h) << 16);
}
__device__ __forceinline__ uint32_t bits_of_bf2(__hip_bfloat162 h) {
    uint32_t u; __builtin_memcpy(&u, &h, 4); return u;
}

// ---- prep: split W into 3 bf16 planes laid out as MFMA B-fragments ----
// B-frag (16x16x32): lane l -> n = l&15, k = (l>>4)*8 + j. Record (s,nt,p):
// 64 lanes x 8 bf16 = 1 KB; record index = s*12 + nt*3 + p.  [R6-verified]
__global__ void prep_kernel(const float* __restrict__ W,
                            const float* __restrict__ se,
                            const int* __restrict__ sidx,
                            unsigned short* __restrict__ Wp,
                            float* __restrict__ tail) {
    if (blockIdx.x == 64) {
        int e = threadIdx.x;
        if (e < 64) {
            const float* emb = se + (*sidx) * SE_DIM;
            float t = 0.f;
            for (int j = 0; j < SE_DIM; ++j)
                t = fmaf(emb[j], W[(size_t)e * K_TOTAL + H_DIM + j], t);
            tail[e] = t;
        }
        return;
    }
    int item = blockIdx.x * 256 + threadIdx.x;   // (s, nt, lane)
    int lane = item & 63;
    int nt   = (item >> 6) & 3;
    int s    = item >> 8;
    int e     = nt * 16 + (lane & 15);
    int kbase = s * 32 + (lane >> 4) * 8;
    const float* wr = W + (size_t)e * K_TOTAL + kbase;
    unsigned short p0[8], p1[8], p2[8];
    #pragma unroll
    for (int j = 0; j < 8; ++j) {
        float v = wr[j];
        unsigned short a0 = bf16_rne(v);
        float r1 = v - bf16_f32(a0);
        unsigned short a1 = bf16_rne(r1);
        float r2 = r1 - bf16_f32(a1);
        p0[j] = a0; p1[j] = a1; p2[j] = bf16_rne(r2);
    }
    size_t rec = (size_t)s * 12 + nt * 3;
    unsigned short* d0 = Wp + (rec + 0) * 512 + lane * 8;
    unsigned short* d1 = Wp + (rec + 1) * 512 + lane * 8;
    unsigned short* d2 = Wp + (rec + 2) * 512 + lane * 8;
    #pragma unroll
    for (int j = 0; j < 8; ++j) { d0[j] = p0[j]; d1[j] = p1[j]; d2[j] = p2[j]; }
}

// split 8 consecutive-k floats into 3 bf16 A-fragment planes (packed pairs)
__device__ __forceinline__ void split3(const float4 fa, const float4 fb,
                                       s16x8& P0, s16x8& P1, s16x8& P2) {
    float f[8] = {fa.x, fa.y, fa.z, fa.w, fb.x, fb.y, fb.z, fb.w};
    uint32_t d0[4], d1[4], d2[4];
    #pragma unroll
    for (int p = 0; p < 4; ++p) {
        float v0 = f[2 * p], v1 = f[2 * p + 1];
        uint32_t u0 = bits_of_bf2(__float22bfloat162_rn(make_float2(v0, v1)));
        float r0 = v0 - __uint_as_float(u0 << 16);
        float r1 = v1 - __uint_as_float(u0 & 0xffff0000u);
        uint32_t u1 = bits_of_bf2(__float22bfloat162_rn(make_float2(r0, r1)));
        float s0 = r0 - __uint_as_float(u1 << 16);
        float s1 = r1 - __uint_as_float(u1 & 0xffff0000u);
        uint32_t u2 = bits_of_bf2(__float22bfloat162_rn(make_float2(s0, s1)));
        d0[p] = u0; d1[p] = u1; d2[p] = u2;
    }
    u32x4 q0 = {d0[0], d0[1], d0[2], d0[3]};
    u32x4 q1 = {d1[0], d1[1], d1[2], d1[3]};
    u32x4 q2 = {d2[0], d2[1], d2[2], d2[3]};
    __builtin_memcpy(&P0, &q0, 16);
    __builtin_memcpy(&P1, &q1, 16);
    __builtin_memcpy(&P2, &q2, 16);
}

// ---- stage 1: kr-pair GEMM, B stationary in LDS, dual-m-tile sharing ----
__launch_bounds__(512)
__global__ void gemm_kernel(const float* __restrict__ x,
                            const unsigned char* __restrict__ Wp,
                            float* __restrict__ logits) {
    __shared__ __align__(16) unsigned char Bs[BSLICE_BYTES];   // 96 KB

    const int tid  = threadIdx.x;                    // 0..511
    const int lane = tid & 63;
    const int wave = __builtin_amdgcn_readfirstlane(tid >> 6);  // 0..7
    const int pr   = blockIdx.x >> 6;                // 0..3 kr-pair
    const int tg   = blockIdx.x & 63;                // 0..63 token group (256)
    const int row  = lane & 15;
    const int quad = lane >> 4;
    const int c    = row;                            // expert col in 16-slice

    // stage one 96 KB B-slice (8 K-steps) for slice kr (lane-linear dst)
    #define STAGE_B(KR) do {                                                \
        const unsigned char* _bs = Wp + (size_t)(KR) * BSLICE_BYTES + tid * 16; \
        _Pragma("unroll")                                                   \
        for (int i = 0; i < 12; ++i)                                        \
            gload_lds16(_bs + i * 8192, &Bs[tid * 16 + i * 8192]);          \
    } while (0)

    STAGE_B(2 * pr);
    asm volatile("s_waitcnt vmcnt(0)" ::: "memory");
    __syncthreads();

    // wave owns 32 tokens = 2 m-tiles; A row pointers for each
    const float* ap0 = x + (size_t)(tg * 256 + wave * 32 + row) * H_DIM
                         + pr * 512 + quad * 8;
    const float* ap1 = ap0 + 16 * H_DIM;

    f32x4 acc00 = {0.f,0.f,0.f,0.f}, acc01 = acc00, acc02 = acc00, acc03 = acc00;
    f32x4 acc10 = acc00, acc11 = acc00, acc12 = acc00, acc13 = acc00;

    // one ks: 12 B-record reads shared by both m-tiles (ds:MFMA = 1:4)
    #define KS_COMPUTE(KSL, A0,A1,A2, C0,C1,C2) do {                        \
        const unsigned char* _bb = &Bs[(KSL) * STEP_BYTES + lane * 16];     \
        {                                                                   \
            s16x8 B0 = *(const s16x8*)(_bb);                                \
            s16x8 B1 = *(const s16x8*)(_bb + 1024);                         \
            s16x8 B2 = *(const s16x8*)(_bb + 2048);                         \
            acc00 = __builtin_amdgcn_mfma_f32_16x16x32_bf16(A0, B0, acc00, 0, 0, 0); \
            acc00 = __builtin_amdgcn_mfma_f32_16x16x32_bf16(A0, B1, acc00, 0, 0, 0); \
            acc00 = __builtin_amdgcn_mfma_f32_16x16x32_bf16(A1, B0, acc00, 0, 0, 0); \
            acc00 = __builtin_amdgcn_mfma_f32_16x16x32_bf16(A0, B2, acc00, 0, 0, 0); \
            acc00 = __builtin_amdgcn_mfma_f32_16x16x32_bf16(A1, B1, acc00, 0, 0, 0); \
            acc00 = __builtin_amdgcn_mfma_f32_16x16x32_bf16(A2, B0, acc00, 0, 0, 0); \
            acc10 = __builtin_amdgcn_mfma_f32_16x16x32_bf16(C0, B0, acc10, 0, 0, 0); \
            acc10 = __builtin_amdgcn_mfma_f32_16x16x32_bf16(C0, B1, acc10, 0, 0, 0); \
            acc10 = __builtin_amdgcn_mfma_f32_16x16x32_bf16(C1, B0, acc10, 0, 0, 0); \
            acc10 = __builtin_amdgcn_mfma_f32_16x16x32_bf16(C0, B2, acc10, 0, 0, 0); \
            acc10 = __builtin_amdgcn_mfma_f32_16x16x32_bf16(C1, B1, acc10, 0, 0, 0); \
            acc10 = __builtin_amdgcn_mfma_f32_16x16x32_bf16(C2, B0, acc10, 0, 0, 0); \
        }                                                                   \
        {                                                                   \
            s16x8 B0 = *(const s16x8*)(_bb + 3072);                         \
            s16x8 B1 = *(const s16x8*)(_bb + 4096);                         \
            s16x8 B2 = *(const s16x8*)(_bb + 5120);                         \
            acc01 = __builtin_amdgcn_mfma_f32_16x16x32_bf16(A0, B0, acc01, 0, 0, 0); \
            acc01 = __builtin_amdgcn_mfma_f32_16x16x32_bf16(A0, B1, acc01, 0, 0, 0); \
            acc01 = __builtin_amdgcn_mfma_f32_16x16x32_bf16(A1, B0, acc01, 0, 0, 0); \
            acc01 = __builtin_amdgcn_mfma_f32_16x16x32_bf16(A0, B2, acc01, 0, 0, 0); \
            acc01 = __builtin_amdgcn_mfma_f32_16x16x32_bf16(A1, B1, acc01, 0, 0, 0); \
            acc01 = __builtin_amdgcn_mfma_f32_16x16x32_bf16(A2, B0, acc01, 0, 0, 0); \
            acc11 = __builtin_amdgcn_mfma_f32_16x16x32_bf16(C0, B0, acc11, 0, 0, 0); \
            acc11 = __builtin_amdgcn_mfma_f32_16x16x32_bf16(C0, B1, acc11, 0, 0, 0); \
            acc11 = __builtin_amdgcn_mfma_f32_16x16x32_bf16(C1, B0, acc11, 0, 0, 0); \
            acc11 = __builtin_amdgcn_mfma_f32_16x16x32_bf16(C0, B2, acc11, 0, 0, 0); \
            acc11 = __builtin_amdgcn_mfma_f32_16x16x32_bf16(C1, B1, acc11, 0, 0, 0); \
            acc11 = __builtin_amdgcn_mfma_f32_16x16x32_bf16(C2, B0, acc11, 0, 0, 0); \
        }                                                                   \
        {                                                                   \
            s16x8 B0 = *(const s16x8*)(_bb + 6144);                         \
            s16x8 B1 = *(const s16x8*)(_bb + 7168);                         \
            s16x8 B2 = *(const s16x8*)(_bb + 8192);                         \
            acc02 = __builtin_amdgcn_mfma_f32_16x16x32_bf16(A0, B0, acc02, 0, 0, 0); \
            acc02 = __builtin_amdgcn_mfma_f32_16x16x32_bf16(A0, B1, acc02, 0, 0, 0); \
            acc02 = __builtin_amdgcn_mfma_f32_16x16x32_bf16(A1, B0, acc02, 0, 0, 0); \
            acc02 = __builtin_amdgcn_mfma_f32_16x16x32_bf16(A0, B2, acc02, 0, 0, 0); \
            acc02 = __builtin_amdgcn_mfma_f32_16x16x32_bf16(A1, B1, acc02, 0, 0, 0); \
            acc02 = __builtin_amdgcn_mfma_f32_16x16x32_bf16(A2, B0, acc02, 0, 0, 0); \
            acc12 = __builtin_amdgcn_mfma_f32_16x16x32_bf16(C0, B0, acc12, 0, 0, 0); \
            acc12 = __builtin_amdgcn_mfma_f32_16x16x32_bf16(C0, B1, acc12, 0, 0, 0); \
            acc12 = __builtin_amdgcn_mfma_f32_16x16x32_bf16(C1, B0, acc12, 0, 0, 0); \
            acc12 = __builtin_amdgcn_mfma_f32_16x16x32_bf16(C0, B2, acc12, 0, 0, 0); \
            acc12 = __builtin_amdgcn_mfma_f32_16x16x32_bf16(C1, B1, acc12, 0, 0, 0); \
            acc12 = __builtin_amdgcn_mfma_f32_16x16x32_bf16(C2, B0, acc12, 0, 0, 0); \
        }                                                                   \
        {                                                                   \
            s16x8 B0 = *(const s16x8*)(_bb + 9216);                         \
            s16x8 B1 = *(const s16x8*)(_bb + 10240);                        \
            s16x8 B2 = *(const s16x8*)(_bb + 11264);                        \
            acc03 = __builtin_amdgcn_mfma_f32_16x16x32_bf16(A0, B0, acc03, 0, 0, 0); \
            acc03 = __builtin_amdgcn_mfma_f32_16x16x32_bf16(A0, B1, acc03, 0, 0, 0); \
            acc03 = __builtin_amdgcn_mfma_f32_16x16x32_bf16(A1, B0, acc03, 0, 0, 0); \
            acc03 = __builtin_amdgcn_mfma_f32_16x16x32_bf16(A0, B2, acc03, 0, 0, 0); \
            acc03 = __builtin_amdgcn_mfma_f32_16x16x32_bf16(A1, B1, acc03, 0, 0, 0); \
            acc03 = __builtin_amdgcn_mfma_f32_16x16x32_bf16(A2, B0, acc03, 0, 0, 0); \
            acc13 = __builtin_amdgcn_mfma_f32_16x16x32_bf16(C0, B0, acc13, 0, 0, 0); \
            acc13 = __builtin_amdgcn_mfma_f32_16x16x32_bf16(C0, B1, acc13, 0, 0, 0); \
            acc13 = __builtin_amdgcn_mfma_f32_16x16x32_bf16(C1, B0, acc13, 0, 0, 0); \
            acc13 = __builtin_amdgcn_mfma_f32_16x16x32_bf16(C0, B2, acc13, 0, 0, 0); \
            acc13 = __builtin_amdgcn_mfma_f32_16x16x32_bf16(C1, B1, acc13, 0, 0, 0); \
            acc13 = __builtin_amdgcn_mfma_f32_16x16x32_bf16(C2, B0, acc13, 0, 0, 0); \
        }                                                                   \
    } while (0)

    // one stage = 8 K-steps = 4 bursts x 2 ks
    #define STAGE_COMPUTE(ST) do {                                          \
        _Pragma("unroll 1")                                                 \
        for (int b = 0; b < 4; ++b) {                                       \
            const int k0 = (ST) * 256 + b * 64;                             \
            float4 a0 = *(const float4*)(ap0 + k0);                         \
            float4 a1 = *(const float4*)(ap0 + k0 + 4);                     \
            float4 a2 = *(const float4*)(ap0 + k0 + 32);                    \
            float4 a3 = *(const float4*)(ap0 + k0 + 36);                    \
            float4 c0 = *(const float4*)(ap1 + k0);                         \
            float4 c1 = *(const float4*)(ap1 + k0 + 4);                     \
            float4 c2 = *(const float4*)(ap1 + k0 + 32);                    \
            float4 c3 = *(const float4*)(ap1 + k0 + 36);                    \
            __builtin_amdgcn_sched_barrier(0);   /* loads stay above */     \
            {                                                               \
                s16x8 A0, A1, A2, C0, C1, C2;                               \
                split3(a0, a1, A0, A1, A2);                                 \
                split3(c0, c1, C0, C1, C2);                                 \
                KS_COMPUTE(b * 2, A0, A1, A2, C0, C1, C2);                  \
            }                                                               \
            {                                                               \
                s16x8 A0, A1, A2, C0, C1, C2;                               \
                split3(a2, a3, A0, A1, A2);                                 \
                split3(c2, c3, C0, C1, C2);                                 \
                KS_COMPUTE(b * 2 + 1, A0, A1, A2, C0, C1, C2);              \
            }                                                               \
        }                                                                   \
    } while (0)

    STAGE_COMPUTE(0);

    // swap in the second kr slice of the pair
    __syncthreads();                     // all waves done reading stage 0
    STAGE_B(2 * pr + 1);
    asm volatile("s_waitcnt vmcnt(0)" ::: "memory");
    __syncthreads();

    STAGE_COMPUTE(1);

    #undef STAGE_COMPUTE
    #undef KS_COMPUTE
    #undef STAGE_B

    // ---- single flush: 32 atomic instrs/wave (4 partials/token-expert) ----
    const int tokb = tg * 256 + wave * 32 + quad * 4;
    float* lg0 = logits + (size_t)tokb * E_DIM + c;          // m-tile 0
    float* lg1 = lg0 + 16 * E_DIM;                           // m-tile 1
    #pragma unroll
    for (int r = 0; r < 4; ++r) {
        atomicAdd(lg0 + r * E_DIM +  0, acc00[r]);
        atomicAdd(lg0 + r * E_DIM + 16, acc01[r]);
        atomicAdd(lg0 + r * E_DIM + 32, acc02[r]);
        atomicAdd(lg0 + r * E_DIM + 48, acc03[r]);
        atomicAdd(lg1 + r * E_DIM +  0, acc10[r]);
        atomicAdd(lg1 + r * E_DIM + 16, acc11[r]);
        atomicAdd(lg1 + r * E_DIM + 32, acc12[r]);
        atomicAdd(lg1 + r * E_DIM + 48, acc13[r]);
    }
}

// ---- stage 2: add tail + noise, top-2, softmax-pair, dense output ----
__launch_bounds__(64, 4)
__global__ void finish_kernel(const float* __restrict__ logits,
                              const float* __restrict__ tail,
                              const float* __restrict__ noise,
                              float* __restrict__ out) {
    const int t = blockIdx.x * 64 + threadIdx.x;     // token 0..16383
    const float4* L4 = (const float4*)(logits + (size_t)t * E_DIM);
    const float4* N4 = (const float4*)(noise  + (size_t)t * E_DIM);
    const float4* T4 = (const float4*)tail;

    float V1 = -3.4e38f, V2 = -3.4e38f;
    int   I1 = 0x7fffffff, I2 = 0x7fffffff;
    #define UPD(V, E) do {                                          \
        float _v = (V); int _e = (E);                               \
        if (_v > V1)      { V2 = V1; I2 = I1; V1 = _v; I1 = _e; }   \
        else if (_v > V2) { V2 = _v; I2 = _e; }                     \
    } while (0)
    #pragma unroll
    for (int i = 0; i < 16; ++i) {
        float4 l = L4[i], n = N4[i], tl = T4[i];
        UPD(l.x + tl.x + 0.1f * n.x, i * 4 + 0);
        UPD(l.y + tl.y + 0.1f * n.y, i * 4 + 1);
        UPD(l.z + tl.z + 0.1f * n.z, i * 4 + 2);
        UPD(l.w + tl.w + 0.1f * n.w, i * 4 + 3);
    }
    #undef UPD
    float d   = expf(V2 - V1);                  // softmax denom cancels
    float inv = 1.0f / (1.0f + d);
    float w1 = inv, w2 = d * inv;

    float4* O4 = (float4*)(out + (size_t)t * E_DIM);
    #pragma unroll
    for (int i = 0; i < 16; ++i) {
        int e = i * 4;
        float4 o;
        o.x = (e + 0 == I1) ? w1 : (e + 0 == I2) ? w2 : 0.0f;
        o.y = (e + 1 == I1) ? w1 : (e + 1 == I2) ? w2 : 0.0f;
        o.z = (e + 2 == I1) ? w1 : (e + 2 == I2) ? w2 : 0.0f;
        o.w = (e + 3 == I1) ? w1 : (e + 3 == I2) ? w2 : 0.0f;
        O4[i] = o;
    }
}

extern "C" void kernel_launch(void* const* d_in, const int* in_sizes, int n_in,
                              void* d_out, int out_size, void* d_ws, size_t ws_size,
                              hipStream_t stream) {
    const float* x     = (const float*)d_in[0];
    const float* se    = (const float*)d_in[1];
    const float* W     = (const float*)d_in[2];
    const float* noise = (const float*)d_in[3];
    const int*   sidx  = (const int*)d_in[4];
    float* out = (float*)d_out;

    unsigned short* Wp     = (unsigned short*)d_ws;                   // 786432 B
    float*          tail   = (float*)((char*)d_ws + WP_TOTAL);        // 256 B
    float*          logits = (float*)((char*)d_ws + LOGITS_OFF);      // 4 MB

    hipMemsetAsync(logits, 0, LOGITS_BYTES, stream);
    hipLaunchKernelGGL(prep_kernel, dim3(65), dim3(256), 0, stream,
                       W, se, sidx, Wp, tail);
    hipLaunchKernelGGL(gemm_kernel, dim3(NPR * 64), dim3(512), 0, stream,
                       x, (const unsigned char*)Wp, logits);
    hipLaunchKernelGGL(finish_kernel, dim3(256), dim3(64), 0, stream,
                       logits, tail, noise, out);
}